// Round 10
// baseline (636.773 us; speedup 1.0000x reference)
//
#include <hip/hip_runtime.h>
#include <hip/hip_bf16.h>
#include <stdint.h>

// ---------- types ----------
typedef __attribute__((ext_vector_type(8))) short short8;   // 8 bf16
typedef __attribute__((ext_vector_type(4))) short short4v;  // 4 bf16 (8 B)
typedef __attribute__((ext_vector_type(4))) float f32x4;
typedef __attribute__((ext_vector_type(4))) float fvec4;

__device__ __forceinline__ short f2bf(float f) {
  unsigned u = __builtin_bit_cast(unsigned, f);
  unsigned r = u + 0x7fffu + ((u >> 16) & 1u);
  return (short)(r >> 16);
}

__device__ __forceinline__ void gload_lds16(const void* g, void* l) {
  __builtin_amdgcn_global_load_lds(
      (const __attribute__((address_space(1))) void*)g,
      (__attribute__((address_space(3))) void*)l, 16, 0, 0);
}

// Problem: x[64,64,500,12], adj[500,500], W[64,576], b[64]; out[64,64,500,12]
// M = I + 0.125*adj. K-axis (k,w): 9*512 = 4608 = 72 kt-tiles of 64.
// Tiled operand layout: tile = [128 r][64 c] bf16, 16 KB, XOR pre-swizzled
// (16B-block j of row r stored at j^(r&7)).
// k=0 B-tiles are identity chunks: only kt = bx*2, bx*2+1 are nonzero per
// block -> biggemm iterates 66 of 72 kt (the 6 zero I-tiles are skipped).
#define VP   512
#define TILE_SHORTS 8192
#define PANEL_TILES 72
#define NSTEP 66

__device__ __forceinline__ int tswz(int r, int c) {
  return r * 64 + ((((c >> 3) ^ (r & 7)) << 3) | (c & 7));
}

// ---------- kernel 1: M^0 (I), M^1 tiles, fp32 master, bf16 M1^T ----------
__global__ __launch_bounds__(256) void initM_kernel(const float* __restrict__ adj,
    float* __restrict__ Mpow, short* __restrict__ Mt, short* __restrict__ M1T) {
  int idx = blockIdx.x * 256 + threadIdx.x;
  int v = idx >> 9, w = idx & 511;
  float m = 0.f;
  if (v < 500 && w < 500) m = 0.125f * adj[v * 500 + w] + (v == w ? 1.f : 0.f);
  Mpow[idx] = m;
  M1T[(size_t)w * VP + v] = f2bf(m);    // transposed bf16 copy for powstep B-frags
  int bx = v >> 7, r = v & 127, c = w & 63;
  int kt0 = (w >> 6), kt1 = 8 + (w >> 6);
  Mt[(size_t)(bx * PANEL_TILES + kt0) * TILE_SHORTS + tswz(r, c)] =
      f2bf((v == w && v < 500) ? 1.f : 0.f);
  Mt[(size_t)(bx * PANEL_TILES + kt1) * TILE_SHORTS + tswz(r, c)] = f2bf(m);
}

// ---------- kernel 2: P = src * M1 (B-frag = one short8 from M1T) ----------
__global__ __launch_bounds__(256) void powstep_kernel(const float* __restrict__ src,
    const short* __restrict__ M1T, float* __restrict__ dst,
    short* __restrict__ Mt, int kslice) {
  int tid = threadIdx.x, wv = tid >> 6, lane = tid & 63;
  int tile = blockIdx.x * 4 + wv;
  int tv = tile >> 5, tw = tile & 31;
  int row  = tv * 16 + (lane & 15);
  int colw = tw * 16 + (lane & 15);
  int kgrp = (lane >> 4) * 8;
  const short* mcol = M1T + (size_t)colw * VP;
  f32x4 acc = {0.f, 0.f, 0.f, 0.f};
  for (int k0 = 0; k0 < 512; k0 += 32) {
    int kc = k0 + kgrp;
    fvec4 f0 = *(const fvec4*)&src[row * VP + kc];
    fvec4 f1 = *(const fvec4*)&src[row * VP + kc + 4];
    short8 a;
    for (int t = 0; t < 4; ++t) { a[t] = f2bf(f0[t]); a[4 + t] = f2bf(f1[t]); }
    short8 b = *(const short8*)&mcol[kc];
    acc = __builtin_amdgcn_mfma_f32_16x16x32_bf16(a, b, acc, 0, 0, 0);
  }
  for (int r = 0; r < 4; ++r) {
    int i = (lane >> 4) * 4 + r;
    int vv = tv * 16 + i;
    float val = acc[r];
    dst[vv * VP + colw] = val;
    int bx = vv >> 7, rr = vv & 127, c = colw & 63;
    int kt = kslice * 8 + (colw >> 6);
    Mt[(size_t)(bx * PANEL_TILES + kt) * TILE_SHORTS + tswz(rr, c)] = f2bf(val);
  }
}

// ---------- kernel 2.5: x transpose: x[n,c,w,l] f32 -> xb[n,l,w512,c64] bf16 ----
__global__ __launch_bounds__(256) void xpose_kernel(const float* __restrict__ x,
    short* __restrict__ xb) {
  int t = threadIdx.x, wv = t >> 6, lane = t & 63;
  int p  = blockIdx.x & 1;          // c-half: 0 or 1
  int w0 = (blockIdx.x >> 1) * 64;  // 0..448
  int n  = blockIdx.y;
  const float* xs = x + (size_t)n * 64 * 6000;
  __shared__ short xl[32 * 770];    // [crow][wl], pitch 770 breaks bank patterns
  for (int ci = 0; ci < 8; ++ci) {
    int crow = wv * 8 + ci;
    int c = p * 32 + crow;
    for (int i = 0; i < 3; ++i) {
      int wl = (i * 64 + lane) * 4;
      int gwl = w0 * 12 + wl;
      fvec4 v = {0.f, 0.f, 0.f, 0.f};
      if (gwl + 3 < 6000) {
        v = *(const fvec4*)&xs[(size_t)c * 6000 + gwl];
      } else {
        for (int e = 0; e < 4; ++e)
          if (gwl + e < 6000) v[e] = xs[(size_t)c * 6000 + gwl + e];
      }
      for (int e = 0; e < 4; ++e) xl[crow * 770 + wl + e] = f2bf(v[e]);
    }
  }
  __syncthreads();
  for (int i = 0; i < 12; ++i) {
    int ct = i * 256 + t;            // 0..3071
    int bl = ct & 3;
    int w_l = (ct >> 2) & 63;
    int l = ct >> 8;                 // 0..11
    short8 s;
    for (int j = 0; j < 8; ++j)
      s[j] = xl[(bl * 8 + j) * 770 + w_l * 12 + l];
    size_t dst = ((size_t)(n * 12 + l) * 512 + w0 + w_l) * 64 + (p * 4 + bl) * 8;
    *(short8*)(xb + dst) = s;
  }
}

// ---------- kernel 3: Z build — pure-register GEMM from xb ----------
__global__ __launch_bounds__(256) void zbuild_kernel(const short* __restrict__ xb,
    const float* __restrict__ W, short* __restrict__ Zt, int n0) {
  int t = threadIdx.x, wv = t >> 6, lane = t & 63;
  int lh = blockIdx.x;             // 0..23: l = lh>>1, w-half = lh&1
  int l = lh >> 1, wh = lh & 1;
  int nloc = blockIdx.y;
  int n = n0 + nloc;
  const short* xbase = xb + (size_t)(n * 12 + l) * 512 * 64;
  short8 af[4][2];
  for (int q = 0; q < 4; ++q)
    for (int ks = 0; ks < 2; ++ks) {
      int wrow = wh * 256 + wv * 64 + q * 16 + (lane & 15);
      int cblk = ks * 4 + (lane >> 4);
      af[q][ks] = *(const short8*)(xbase + (size_t)wrow * 64 + cblk * 8);
    }
  int lanebase = (lane & 15) * 12 + l;
  int kt_off = wh * 4 + wv;
  for (int j = 0; j < 36; ++j) {
    int k = j >> 2;
    int o = (j & 3) * 16 + (lane & 15);
    const float* wp = W + o * 576 + k * 64;
    short8 bw[2];
    for (int ks = 0; ks < 2; ++ks) {
      fvec4 f0 = *(const fvec4*)(wp + ks * 32 + (lane >> 4) * 8);
      fvec4 f1 = *(const fvec4*)(wp + ks * 32 + (lane >> 4) * 8 + 4);
      for (int e = 0; e < 4; ++e) { bw[ks][e] = f2bf(f0[e]); bw[ks][4 + e] = f2bf(f1[e]); }
    }
    f32x4 acc[4];
    for (int q = 0; q < 4; ++q) {
      acc[q] = (f32x4){0.f, 0.f, 0.f, 0.f};
      acc[q] = __builtin_amdgcn_mfma_f32_16x16x32_bf16(af[q][0], bw[0], acc[q], 0, 0, 0);
      acc[q] = __builtin_amdgcn_mfma_f32_16x16x32_bf16(af[q][1], bw[1], acc[q], 0, 0, 0);
    }
    int zr = (j & 3) * 192 + lanebase;
    int pr = zr >> 7, rr = zr & 127;
    size_t tbase = ((size_t)(nloc * 6 + pr) * PANEL_TILES + k * 8 + kt_off) * TILE_SHORTS
                 + rr * 64;
    for (int q = 0; q < 4; ++q) {
      int c4 = q * 16 + (lane >> 4) * 4;
      size_t idx = tbase + ((((c4 >> 3) ^ (zr & 7)) << 3) | (c4 & 7));
      short4v s;
      for (int e = 0; e < 4; ++e) s[e] = f2bf(acc[q][e]);
      *(short4v*)(Zt + idx) = s;
    }
  }
}

// ---------- kernel 4: big batched GEMM (R7/R9 pipeline + zero-I-tile skip) ----
__global__ __launch_bounds__(256) void biggemm_kernel(const short* __restrict__ Zt,
    const short* __restrict__ Mt, const float* __restrict__ bvec,
    float* __restrict__ out, int n0) {
  int tid = threadIdx.x, wv = tid >> 6, lane = tid & 63;
  int nwg = gridDim.x;
  int b = blockIdx.x;
  int swz = (b & 7) * (nwg >> 3) + (b >> 3);   // nwg = 24*cn, always % 8 == 0
  int bx = swz & 3;
  int rest = swz >> 2;
  int by = rest % 6;
  int bz = rest / 6;
  int v0    = bx * 128;
  int rowM0 = by * 128;
  int n = n0 + bz;
  __shared__ short As[2][TILE_SHORTS];   // 2 x 16 KiB
  __shared__ short Bs[2][TILE_SHORTS];   // 2 x 16 KiB (64 KiB total)
  f32x4 acc[4][4];
  for (int i = 0; i < 4; ++i)
    for (int j = 0; j < 4; ++j) acc[i][j] = (f32x4){0.f, 0.f, 0.f, 0.f};
  int wr = wv >> 1, wc = wv & 1;
  const char* Apanel = (const char*)(Zt + (size_t)(bz * 6 + by) * PANEL_TILES * TILE_SHORTS);
  const char* Bpanel = (const char*)(Mt + (size_t)bx * PANEL_TILES * TILE_SHORTS);

  // step -> kt map: k=0 B-tiles are identity chunks; only kt = bx*2, bx*2+1
  // are nonzero for this block. Steps 0,1 cover those; steps 2.. cover kt 8..71.
  auto ktmap = [&](int s) { return (s < 2) ? (bx * 2 + s) : (s + 6); };

  auto STAGE = [&](int p, int kt) {
    const char* a  = Apanel + (size_t)kt * (TILE_SHORTS * 2);
    const char* bb = Bpanel + (size_t)kt * (TILE_SHORTS * 2);
#pragma unroll
    for (int cc = 0; cc < 4; ++cc) {
      int chunk = cc * 4 + wv;
      int off = chunk * 1024 + lane * 16;   // linear 1KB per instruction
      gload_lds16(a + off,  (char*)As[p] + chunk * 1024);
      gload_lds16(bb + off, (char*)Bs[p] + chunk * 1024);
    }
  };

  // prologue: two K-steps in flight (16 outstanding gloads/wave)
  STAGE(0, ktmap(0));
  STAGE(1, ktmap(1));

  for (int s = 0; s < NSTEP; ++s) {
    int d = s & 1;
    // wait step s's 8 loads; keep s+1's 8 in flight (never 0 mid-loop)
    if (s < NSTEP - 1) {
      asm volatile("s_waitcnt vmcnt(8)" ::: "memory");
    } else {
      asm volatile("s_waitcnt vmcnt(0)" ::: "memory");
    }
    __builtin_amdgcn_sched_barrier(0);
    __builtin_amdgcn_s_barrier();          // dbuf[d] visible to all waves

    // read ALL fragments for this K-step into registers
    short8 af[2][4], bf[2][4];
#pragma unroll
    for (int kk = 0; kk < 2; ++kk) {
      int cbyte = kk * 64 + (lane >> 4) * 16;
#pragma unroll
      for (int mi = 0; mi < 4; ++mi) {
        int r = wr * 64 + mi * 16 + (lane & 15);
        af[kk][mi] = *(const short8*)((const char*)As[d] + r * 128 + (cbyte ^ ((r & 7) << 4)));
      }
#pragma unroll
      for (int ni = 0; ni < 4; ++ni) {
        int r = wc * 64 + ni * 16 + (lane & 15);
        bf[kk][ni] = *(const short8*)((const char*)Bs[d] + r * 128 + (cbyte ^ ((r & 7) << 4)));
      }
    }
    asm volatile("s_waitcnt lgkmcnt(0)" ::: "memory");   // this wave's reads done
    __builtin_amdgcn_sched_barrier(0);
    __builtin_amdgcn_s_barrier();          // ALL waves' reads done -> dbuf[d] dead

    // issue next-next K-step into the freed buffer; lands under MFMA
    if (s + 2 < NSTEP) STAGE(d, ktmap(s + 2));

    __builtin_amdgcn_s_setprio(1);
#pragma unroll
    for (int kk = 0; kk < 2; ++kk)
#pragma unroll
      for (int mi = 0; mi < 4; ++mi)
#pragma unroll
        for (int ni = 0; ni < 4; ++ni)
          acc[mi][ni] = __builtin_amdgcn_mfma_f32_16x16x32_bf16(af[kk][mi], bf[kk][ni],
                                                                acc[mi][ni], 0, 0, 0);
    __builtin_amdgcn_s_setprio(0);
  }

  for (int mi = 0; mi < 4; ++mi) {
    for (int r = 0; r < 4; ++r) {
      int gm = rowM0 + wr * 64 + mi * 16 + (lane >> 4) * 4 + r;
      int o = gm / 12, l = gm - o * 12;
      float bo = bvec[o];
      size_t obase = (((size_t)n * 64 + o) * 500) * 12 + l;
      for (int ni = 0; ni < 4; ++ni) {
        int v = v0 + wc * 64 + ni * 16 + (lane & 15);
        if (v < 500) out[obase + (size_t)v * 12] = acc[mi][ni][r] + bo;
      }
    }
  }
}

// ---------- host ----------
extern "C" void kernel_launch(void* const* d_in, const int* in_sizes, int n_in,
                              void* d_out, int out_size, void* d_ws, size_t ws_size,
                              hipStream_t stream) {
  const float* x   = (const float*)d_in[0];
  const float* adj = (const float*)d_in[1];
  const float* W   = (const float*)d_in[2];
  const float* bv  = (const float*)d_in[3];
  float* out = (float*)d_out;
  char* ws = (char*)d_ws;

  size_t off = 0;
  float* Mpow0 = (float*)(ws + off); off += (size_t)512 * 512 * 4;
  float* Mpow1 = (float*)(ws + off); off += (size_t)512 * 512 * 4;
  short* M1T   = (short*)(ws + off); off += (size_t)512 * 512 * 2;   // 0.5 MiB
  short* Mt    = (short*)(ws + off); off += (size_t)4 * PANEL_TILES * TILE_SHORTS * 2;
  short* xb    = (short*)(ws + off); off += (size_t)64 * 12 * 512 * 64 * 2;  // 50.3 MB
  short* Zt    = (short*)(ws + off);
  size_t per_n = (size_t)6 * PANEL_TILES * TILE_SHORTS * 2;          // 7,077,888 B
  int nchunk = 1;
  if (ws_size > off) {
    size_t a = (ws_size - off) / per_n;
    nchunk = (a >= 64) ? 64 : (a < 1 ? 1 : (int)a);   // single dispatch if ws allows
  }

  hipLaunchKernelGGL(initM_kernel, dim3(1024), dim3(256), 0, stream, adj, Mpow0, Mt, M1T);
  const float* src = Mpow0; float* dst = Mpow1;
  for (int k = 2; k <= 8; ++k) {
    hipLaunchKernelGGL(powstep_kernel, dim3(256), dim3(256), 0, stream, src, M1T, dst, Mt, k);
    float* t = dst; dst = (float*)src; src = t;
  }
  hipLaunchKernelGGL(xpose_kernel, dim3(16, 64), dim3(256), 0, stream, x, xb);
  for (int n0 = 0; n0 < 64; n0 += nchunk) {
    int cn = (64 - n0) < nchunk ? (64 - n0) : nchunk;
    hipLaunchKernelGGL(zbuild_kernel, dim3(24, cn), dim3(256), 0, stream, xb, W, Zt, n0);
    hipLaunchKernelGGL(biggemm_kernel, dim3(24 * cn), dim3(256), 0, stream, Zt, Mt, bv, out, n0);
  }
}

// Round 11
// 584.296 us; speedup vs baseline: 1.0898x; 1.0898x over previous
//
#include <hip/hip_runtime.h>
#include <hip/hip_bf16.h>
#include <stdint.h>

// ---------- types ----------
typedef __attribute__((ext_vector_type(8))) short short8;   // 8 bf16
typedef __attribute__((ext_vector_type(4))) short short4v;  // 4 bf16 (8 B)
typedef __attribute__((ext_vector_type(4))) float f32x4;
typedef __attribute__((ext_vector_type(4))) float fvec4;

__device__ __forceinline__ short f2bf(float f) {
  unsigned u = __builtin_bit_cast(unsigned, f);
  unsigned r = u + 0x7fffu + ((u >> 16) & 1u);
  return (short)(r >> 16);
}

__device__ __forceinline__ void gload_lds16(const void* g, void* l) {
  __builtin_amdgcn_global_load_lds(
      (const __attribute__((address_space(1))) void*)g,
      (__attribute__((address_space(3))) void*)l, 16, 0, 0);
}

// Problem: x[64,64,500,12], adj[500,500], W[64,576], b[64]; out[64,64,500,12]
// M = I + 0.125*adj. K-axis (k,w): 9*512 = 4608 = 72 kt-tiles of 64.
// Tiled operand layout: tile = [128 r][64 c] bf16, 16 KB, XOR pre-swizzled
// (16B-block j of row r stored at j^(r&7)).
// k=0 B-tiles are identity chunks: only kt = bx*2, bx*2+1 are nonzero per
// block -> biggemm iterates 66 of 72 kt (the 6 zero I-tiles are skipped).
// nchunk=16 keeps the Z chunk (113 MB) Infinity-Cache-resident: zbuild's
// writes and biggemm's reads never round-trip HBM (R10 regression proved
// this is worth ~140 us).
#define VP   512
#define TILE_SHORTS 8192
#define PANEL_TILES 72
#define NSTEP 66

__device__ __forceinline__ int tswz(int r, int c) {
  return r * 64 + ((((c >> 3) ^ (r & 7)) << 3) | (c & 7));
}

// ---------- kernel 1: M^0 (I), M^1 tiles, fp32 master, bf16 M1^T ----------
__global__ __launch_bounds__(256) void initM_kernel(const float* __restrict__ adj,
    float* __restrict__ Mpow, short* __restrict__ Mt, short* __restrict__ M1T) {
  int idx = blockIdx.x * 256 + threadIdx.x;
  int v = idx >> 9, w = idx & 511;
  float m = 0.f;
  if (v < 500 && w < 500) m = 0.125f * adj[v * 500 + w] + (v == w ? 1.f : 0.f);
  Mpow[idx] = m;
  M1T[(size_t)w * VP + v] = f2bf(m);    // transposed bf16 copy for powstep B-frags
  int bx = v >> 7, r = v & 127, c = w & 63;
  int kt0 = (w >> 6), kt1 = 8 + (w >> 6);
  Mt[(size_t)(bx * PANEL_TILES + kt0) * TILE_SHORTS + tswz(r, c)] =
      f2bf((v == w && v < 500) ? 1.f : 0.f);
  Mt[(size_t)(bx * PANEL_TILES + kt1) * TILE_SHORTS + tswz(r, c)] = f2bf(m);
}

// ---------- kernel 2: P = src * M1 (B-frag = one short8 from M1T) ----------
__global__ __launch_bounds__(256) void powstep_kernel(const float* __restrict__ src,
    const short* __restrict__ M1T, float* __restrict__ dst,
    short* __restrict__ Mt, int kslice) {
  int tid = threadIdx.x, wv = tid >> 6, lane = tid & 63;
  int tile = blockIdx.x * 4 + wv;
  int tv = tile >> 5, tw = tile & 31;
  int row  = tv * 16 + (lane & 15);
  int colw = tw * 16 + (lane & 15);
  int kgrp = (lane >> 4) * 8;
  const short* mcol = M1T + (size_t)colw * VP;
  f32x4 acc = {0.f, 0.f, 0.f, 0.f};
  for (int k0 = 0; k0 < 512; k0 += 32) {
    int kc = k0 + kgrp;
    fvec4 f0 = *(const fvec4*)&src[row * VP + kc];
    fvec4 f1 = *(const fvec4*)&src[row * VP + kc + 4];
    short8 a;
    for (int t = 0; t < 4; ++t) { a[t] = f2bf(f0[t]); a[4 + t] = f2bf(f1[t]); }
    short8 b = *(const short8*)&mcol[kc];
    acc = __builtin_amdgcn_mfma_f32_16x16x32_bf16(a, b, acc, 0, 0, 0);
  }
  for (int r = 0; r < 4; ++r) {
    int i = (lane >> 4) * 4 + r;
    int vv = tv * 16 + i;
    float val = acc[r];
    dst[vv * VP + colw] = val;
    int bx = vv >> 7, rr = vv & 127, c = colw & 63;
    int kt = kslice * 8 + (colw >> 6);
    Mt[(size_t)(bx * PANEL_TILES + kt) * TILE_SHORTS + tswz(rr, c)] = f2bf(val);
  }
}

// ---------- kernel 2.5: x transpose: x[n,c,w,l] f32 -> xb[n,l,w512,c64] bf16 ----
__global__ __launch_bounds__(256) void xpose_kernel(const float* __restrict__ x,
    short* __restrict__ xb) {
  int t = threadIdx.x, wv = t >> 6, lane = t & 63;
  int p  = blockIdx.x & 1;          // c-half: 0 or 1
  int w0 = (blockIdx.x >> 1) * 64;  // 0..448
  int n  = blockIdx.y;
  const float* xs = x + (size_t)n * 64 * 6000;
  __shared__ short xl[32 * 770];    // [crow][wl], pitch 770 breaks bank patterns
  for (int ci = 0; ci < 8; ++ci) {
    int crow = wv * 8 + ci;
    int c = p * 32 + crow;
    for (int i = 0; i < 3; ++i) {
      int wl = (i * 64 + lane) * 4;
      int gwl = w0 * 12 + wl;
      fvec4 v = {0.f, 0.f, 0.f, 0.f};
      if (gwl + 3 < 6000) {
        v = *(const fvec4*)&xs[(size_t)c * 6000 + gwl];
      } else {
        for (int e = 0; e < 4; ++e)
          if (gwl + e < 6000) v[e] = xs[(size_t)c * 6000 + gwl + e];
      }
      for (int e = 0; e < 4; ++e) xl[crow * 770 + wl + e] = f2bf(v[e]);
    }
  }
  __syncthreads();
  for (int i = 0; i < 12; ++i) {
    int ct = i * 256 + t;            // 0..3071
    int bl = ct & 3;
    int w_l = (ct >> 2) & 63;
    int l = ct >> 8;                 // 0..11
    short8 s;
    for (int j = 0; j < 8; ++j)
      s[j] = xl[(bl * 8 + j) * 770 + w_l * 12 + l];
    size_t dst = ((size_t)(n * 12 + l) * 512 + w0 + w_l) * 64 + (p * 4 + bl) * 8;
    *(short8*)(xb + dst) = s;
  }
}

// ---------- kernel 3: Z build — pure-register GEMM from xb ----------
__global__ __launch_bounds__(256) void zbuild_kernel(const short* __restrict__ xb,
    const float* __restrict__ W, short* __restrict__ Zt, int n0) {
  int t = threadIdx.x, wv = t >> 6, lane = t & 63;
  int lh = blockIdx.x;             // 0..23: l = lh>>1, w-half = lh&1
  int l = lh >> 1, wh = lh & 1;
  int nloc = blockIdx.y;
  int n = n0 + nloc;
  const short* xbase = xb + (size_t)(n * 12 + l) * 512 * 64;
  short8 af[4][2];
  for (int q = 0; q < 4; ++q)
    for (int ks = 0; ks < 2; ++ks) {
      int wrow = wh * 256 + wv * 64 + q * 16 + (lane & 15);
      int cblk = ks * 4 + (lane >> 4);
      af[q][ks] = *(const short8*)(xbase + (size_t)wrow * 64 + cblk * 8);
    }
  int lanebase = (lane & 15) * 12 + l;
  int kt_off = wh * 4 + wv;
  for (int j = 0; j < 36; ++j) {
    int k = j >> 2;
    int o = (j & 3) * 16 + (lane & 15);
    const float* wp = W + o * 576 + k * 64;
    short8 bw[2];
    for (int ks = 0; ks < 2; ++ks) {
      fvec4 f0 = *(const fvec4*)(wp + ks * 32 + (lane >> 4) * 8);
      fvec4 f1 = *(const fvec4*)(wp + ks * 32 + (lane >> 4) * 8 + 4);
      for (int e = 0; e < 4; ++e) { bw[ks][e] = f2bf(f0[e]); bw[ks][4 + e] = f2bf(f1[e]); }
    }
    f32x4 acc[4];
    for (int q = 0; q < 4; ++q) {
      acc[q] = (f32x4){0.f, 0.f, 0.f, 0.f};
      acc[q] = __builtin_amdgcn_mfma_f32_16x16x32_bf16(af[q][0], bw[0], acc[q], 0, 0, 0);
      acc[q] = __builtin_amdgcn_mfma_f32_16x16x32_bf16(af[q][1], bw[1], acc[q], 0, 0, 0);
    }
    int zr = (j & 3) * 192 + lanebase;
    int pr = zr >> 7, rr = zr & 127;
    size_t tbase = ((size_t)(nloc * 6 + pr) * PANEL_TILES + k * 8 + kt_off) * TILE_SHORTS
                 + rr * 64;
    for (int q = 0; q < 4; ++q) {
      int c4 = q * 16 + (lane >> 4) * 4;
      size_t idx = tbase + ((((c4 >> 3) ^ (zr & 7)) << 3) | (c4 & 7));
      short4v s;
      for (int e = 0; e < 4; ++e) s[e] = f2bf(acc[q][e]);
      *(short4v*)(Zt + idx) = s;
    }
  }
}

// ---------- kernel 4: big batched GEMM (R7 pipeline + I-tile skip) ----------
__global__ __launch_bounds__(256) void biggemm_kernel(const short* __restrict__ Zt,
    const short* __restrict__ Mt, const float* __restrict__ bvec,
    float* __restrict__ out, int n0) {
  int tid = threadIdx.x, wv = tid >> 6, lane = tid & 63;
  int nwg = gridDim.x;
  int b = blockIdx.x;
  int swz = (b & 7) * (nwg >> 3) + (b >> 3);   // nwg = 24*cn, always % 8 == 0
  int bx = swz & 3;
  int rest = swz >> 2;
  int by = rest % 6;
  int bz = rest / 6;
  int v0    = bx * 128;
  int rowM0 = by * 128;
  int n = n0 + bz;
  __shared__ short As[2][TILE_SHORTS];   // 2 x 16 KiB
  __shared__ short Bs[2][TILE_SHORTS];   // 2 x 16 KiB (64 KiB total)
  f32x4 acc[4][4];
  for (int i = 0; i < 4; ++i)
    for (int j = 0; j < 4; ++j) acc[i][j] = (f32x4){0.f, 0.f, 0.f, 0.f};
  int wr = wv >> 1, wc = wv & 1;
  const char* Apanel = (const char*)(Zt + (size_t)(bz * 6 + by) * PANEL_TILES * TILE_SHORTS);
  const char* Bpanel = (const char*)(Mt + (size_t)bx * PANEL_TILES * TILE_SHORTS);

  // step -> kt map: k=0 B-tiles are identity chunks; only kt = bx*2, bx*2+1
  // are nonzero for this block. Steps 0,1 cover those; steps 2.. cover kt 8..71.
  auto ktmap = [&](int s) { return (s < 2) ? (bx * 2 + s) : (s + 6); };

  auto STAGE = [&](int p, int kt) {
    const char* a  = Apanel + (size_t)kt * (TILE_SHORTS * 2);
    const char* bb = Bpanel + (size_t)kt * (TILE_SHORTS * 2);
#pragma unroll
    for (int cc = 0; cc < 4; ++cc) {
      int chunk = cc * 4 + wv;
      int off = chunk * 1024 + lane * 16;   // linear 1KB per instruction
      gload_lds16(a + off,  (char*)As[p] + chunk * 1024);
      gload_lds16(bb + off, (char*)Bs[p] + chunk * 1024);
    }
  };

  // prologue: two K-steps in flight (16 outstanding gloads/wave)
  STAGE(0, ktmap(0));
  STAGE(1, ktmap(1));

  for (int s = 0; s < NSTEP; ++s) {
    int d = s & 1;
    // wait step s's 8 loads; keep s+1's 8 in flight (never 0 mid-loop)
    if (s < NSTEP - 1) {
      asm volatile("s_waitcnt vmcnt(8)" ::: "memory");
    } else {
      asm volatile("s_waitcnt vmcnt(0)" ::: "memory");
    }
    __builtin_amdgcn_sched_barrier(0);
    __builtin_amdgcn_s_barrier();          // dbuf[d] visible to all waves

    // read ALL fragments for this K-step into registers
    short8 af[2][4], bf[2][4];
#pragma unroll
    for (int kk = 0; kk < 2; ++kk) {
      int cbyte = kk * 64 + (lane >> 4) * 16;
#pragma unroll
      for (int mi = 0; mi < 4; ++mi) {
        int r = wr * 64 + mi * 16 + (lane & 15);
        af[kk][mi] = *(const short8*)((const char*)As[d] + r * 128 + (cbyte ^ ((r & 7) << 4)));
      }
#pragma unroll
      for (int ni = 0; ni < 4; ++ni) {
        int r = wc * 64 + ni * 16 + (lane & 15);
        bf[kk][ni] = *(const short8*)((const char*)Bs[d] + r * 128 + (cbyte ^ ((r & 7) << 4)));
      }
    }
    asm volatile("s_waitcnt lgkmcnt(0)" ::: "memory");   // this wave's reads done
    __builtin_amdgcn_sched_barrier(0);
    __builtin_amdgcn_s_barrier();          // ALL waves' reads done -> dbuf[d] dead

    // issue next-next K-step into the freed buffer; lands under MFMA
    if (s + 2 < NSTEP) STAGE(d, ktmap(s + 2));

    __builtin_amdgcn_s_setprio(1);
#pragma unroll
    for (int kk = 0; kk < 2; ++kk)
#pragma unroll
      for (int mi = 0; mi < 4; ++mi)
#pragma unroll
        for (int ni = 0; ni < 4; ++ni)
          acc[mi][ni] = __builtin_amdgcn_mfma_f32_16x16x32_bf16(af[kk][mi], bf[kk][ni],
                                                                acc[mi][ni], 0, 0, 0);
    __builtin_amdgcn_s_setprio(0);
  }

  for (int mi = 0; mi < 4; ++mi) {
    for (int r = 0; r < 4; ++r) {
      int gm = rowM0 + wr * 64 + mi * 16 + (lane >> 4) * 4 + r;
      int o = gm / 12, l = gm - o * 12;
      float bo = bvec[o];
      size_t obase = (((size_t)n * 64 + o) * 500) * 12 + l;
      for (int ni = 0; ni < 4; ++ni) {
        int v = v0 + wc * 64 + ni * 16 + (lane & 15);
        if (v < 500) out[obase + (size_t)v * 12] = acc[mi][ni][r] + bo;
      }
    }
  }
}

// ---------- host ----------
extern "C" void kernel_launch(void* const* d_in, const int* in_sizes, int n_in,
                              void* d_out, int out_size, void* d_ws, size_t ws_size,
                              hipStream_t stream) {
  const float* x   = (const float*)d_in[0];
  const float* adj = (const float*)d_in[1];
  const float* W   = (const float*)d_in[2];
  const float* bv  = (const float*)d_in[3];
  float* out = (float*)d_out;
  char* ws = (char*)d_ws;

  size_t off = 0;
  float* Mpow0 = (float*)(ws + off); off += (size_t)512 * 512 * 4;
  float* Mpow1 = (float*)(ws + off); off += (size_t)512 * 512 * 4;
  short* M1T   = (short*)(ws + off); off += (size_t)512 * 512 * 2;   // 0.5 MiB
  short* Mt    = (short*)(ws + off); off += (size_t)4 * PANEL_TILES * TILE_SHORTS * 2;
  short* xb    = (short*)(ws + off); off += (size_t)64 * 12 * 512 * 64 * 2;  // 50.3 MB
  short* Zt    = (short*)(ws + off);
  size_t per_n = (size_t)6 * PANEL_TILES * TILE_SHORTS * 2;          // 7,077,888 B
  int nchunk = 1;
  if (ws_size > off) {
    size_t a = (ws_size - off) / per_n;
    nchunk = (a >= 16) ? 16 : (a < 1 ? 1 : (int)a);   // 16 -> Z chunk 113 MB, L3-fits
  }

  hipLaunchKernelGGL(initM_kernel, dim3(1024), dim3(256), 0, stream, adj, Mpow0, Mt, M1T);
  const float* src = Mpow0; float* dst = Mpow1;
  for (int k = 2; k <= 8; ++k) {
    hipLaunchKernelGGL(powstep_kernel, dim3(256), dim3(256), 0, stream, src, M1T, dst, Mt, k);
    float* t = dst; dst = (float*)src; src = t;
  }
  hipLaunchKernelGGL(xpose_kernel, dim3(16, 64), dim3(256), 0, stream, x, xb);
  for (int n0 = 0; n0 < 64; n0 += nchunk) {
    int cn = (64 - n0) < nchunk ? (64 - n0) : nchunk;
    hipLaunchKernelGGL(zbuild_kernel, dim3(24, cn), dim3(256), 0, stream, xb, W, Zt, n0);
    hipLaunchKernelGGL(biggemm_kernel, dim3(24 * cn), dim3(256), 0, stream, Zt, Mt, bv, out, n0);
  }
}